// Round 10
// baseline (1782.811 us; speedup 1.0000x reference)
//
#include <hip/hip_runtime.h>
#include <cstdint>
#include <cstddef>

// ===========================================================================
// ActionDecoder on MI355X — round 10: revert to PROVEN r7 protocol
// (flag-based, passed at 2.62us/step) + two safe upgrades.
// Topology: 64 WGs, WG w = (BG = w>>4, CG = w&15) owns batch-group BG
// (16 batches) x col-group CG (32 h-cols = 128 gate rows of W_hh). Wave wv
// takes K-chunk [128wv,128wv+128): B-frags in 128 VGPRs; split-K partial S
// reduced in LDS. Cross-WG: h as f16 via relaxed agent-scope intrinsic
// stores (IC-coherent), flags via same intrinsics. NO raw-asm stores, NO
// tagged data (r8/r9's deterministic failure reverted wholesale).
// r10 changes vs r7:
//  (1) PER-WAVE flags: wave wv's gate threads cover batches 4wv..4wv+3, so
//      its flag certifies exactly those rows. Release = wave-local
//      s_waitcnt vmcnt(0) + lane0 flag store — the second __syncthreads is
//      gone (one barrier/step, for the split-K reduction only). Consumers
//      poll 16 flags (4 producer CGs x 4 waves). Safety: passing poll t
//      proves all 64 row-wave flags >= t+1 => all step-(t-1) reads of the
//      buffer about to be overwritten completed; barrier(t) publishes this
//      to all waves before any h_{t+1} store. Spart double-buffered so the
//      reduce (no trailing barrier) never races next step's writes.
//  (2) Spart pitch 17 (odd): r7's pitch 20 gave cq*20 = {0,8,16,24} mod 32
//      => 4-way read conflicts (measured 2.5e7 cycles). Pitch 17 -> 2-way
//      max on reads (free per m136).
// ===========================================================================

typedef _Float16     f16x8 __attribute__((ext_vector_type(8)));
typedef _Float16     f16x2 __attribute__((ext_vector_type(2)));
typedef float        f32x4 __attribute__((ext_vector_type(4)));
typedef float        f32x2 __attribute__((ext_vector_type(2)));
typedef unsigned int u32x4 __attribute__((ext_vector_type(4)));

#define TPB 256
#define NWG 64

// ---- ws layout (bytes) ----
#define WS_GX0   0          // 64*2048 f32   = 524288
#define WS_P     524288     // 512*2048 f32  = 4194304
#define WS_HN    4718592    // 64*512 f32    = 131072
#define WS_HBUF  4849664    // 2*64*512 f16  = 131072
#define WS_FLAGS 4980736    // 64 WG x 4 waves x 64B = 16384

__device__ __forceinline__ float sigm_(float x) { return 1.f / (1.f + __expf(-x)); }
__device__ __forceinline__ float tanh_(float x) {
    const float e = __expf(-2.f * fabsf(x));
    return copysignf((1.f - e) / (1.f + e), x);
}

// agent-scope (IC-coherent) relaxed accessors — proven r3..r7 primitives
__device__ __forceinline__ void st_ic_u32(unsigned int* p, unsigned int v) {
    __hip_atomic_store(p, v, __ATOMIC_RELAXED, __HIP_MEMORY_SCOPE_AGENT);
}
__device__ __forceinline__ unsigned int ld_ic_u32(const unsigned int* p) {
    return __hip_atomic_load(p, __ATOMIC_RELAXED, __HIP_MEMORY_SCOPE_AGENT);
}

// ---------------------------------------------------------------------------
// Generic f32 tiled GEMM: C[M,N] = A[M,K] @ B[N,K]^T (+bias1+bias2 on z==0).
// ---------------------------------------------------------------------------
__global__ void gemm_nt_bias(const float* __restrict__ A, int lda,
                             const float* __restrict__ B, int ldb,
                             float* __restrict__ C, int ldc, int K,
                             const float* __restrict__ bias1,
                             const float* __restrict__ bias2)
{
    __shared__ float As[32 * 68];
    __shared__ float Bs[32 * 68];
    const int tid = threadIdx.x;
    const int m0 = blockIdx.y * 64, n0 = blockIdx.x * 64;
    const int kchunk = K / gridDim.z;
    const int kbeg = blockIdx.z * kchunk, kend = kbeg + kchunk;
    const int tr = tid >> 4, tc = tid & 15;
    float acc[4][4] = {};

    for (int k0 = kbeg; k0 < kend; k0 += 32) {
        __syncthreads();
        #pragma unroll
        for (int idx = tid; idx < 2048; idx += TPB) {
            const int r = idx >> 5, kk = idx & 31;
            As[kk * 68 + r] = A[(size_t)(m0 + r) * lda + k0 + kk];
            Bs[kk * 68 + r] = B[(size_t)(n0 + r) * ldb + k0 + kk];
        }
        __syncthreads();
        #pragma unroll
        for (int kk = 0; kk < 32; ++kk) {
            const f32x4 a = *(const f32x4*)&As[kk * 68 + tr * 4];
            const f32x4 b = *(const f32x4*)&Bs[kk * 68 + tc * 4];
            #pragma unroll
            for (int i = 0; i < 4; ++i)
                #pragma unroll
                for (int j = 0; j < 4; ++j)
                    acc[i][j] = fmaf(a[i], b[j], acc[i][j]);
        }
    }

    const bool split = (gridDim.z > 1);
    #pragma unroll
    for (int i = 0; i < 4; ++i) {
        const int m = m0 + tr * 4 + i;
        #pragma unroll
        for (int j = 0; j < 4; ++j) {
            const int n = n0 + tc * 4 + j;
            float v = acc[i][j];
            if (blockIdx.z == 0) {
                if (bias1) v += bias1[n];
                if (bias2) v += bias2[n];
            }
            if (split) atomicAdd(&C[(size_t)m * ldc + n], v);
            else       C[(size_t)m * ldc + n] = v;
        }
    }
}

// ---------------------------------------------------------------------------
// LSTM recurrence. 64 WGs x 256 threads. Per-wave flags, ONE barrier/step.
// ---------------------------------------------------------------------------
__global__ void __launch_bounds__(TPB, 1)
lstm_seq(const float* __restrict__ Whh,   // [2048,512] f32
         const float* __restrict__ GX0,   // [64,2048] f32 (ws)
         const float* __restrict__ P,     // [512,2048] f32 (ws)
         const int*   __restrict__ x2,    // [64,512]
         const int*   __restrict__ lens,  // [64]
         _Float16*    hbuf,               // [2][64*512] f16 (ws, IC-resident)
         float*       __restrict__ hn,    // [64,512] f32 (ws)
         unsigned int* flags)             // [64 wg][4 wv] spaced 64B
{
    // Spart[buf][wv][rowloc(128)][batch(16)+pad1], pitch 17 => 69632 B
    __shared__ float Spart[2][4 * 128 * 17];

    const int tid = threadIdx.x, wg = blockIdx.x;
    const int lane = tid & 63, wv = tid >> 6;
    const int BG = wg >> 4;               // batch group 0..3
    const int CG = wg & 15;               // col group 0..15
    const int m16 = lane & 15, q = lane >> 4;

    // ---- gate-thread geometry: thread -> (batch-loc, 2 adjacent cols) ----
    // wave wv's threads have bl in [4wv, 4wv+4) — matches per-wave flag.
    const int bl  = tid >> 4;             // 0..15 batch-local
    const int cq  = (tid & 15) * 2;       // 0,2,..,30 col-local
    const int b   = BG * 16 + bl;
    const int col = CG * 32 + cq;
    const int last = lens[b] - 1;
    const int* toks = x2 + b * 512;

    // ---- time-invariant gate inputs from GX0 (hoisted) ----
    f32x2 gxv[4];
    {
        const float* gx = GX0 + (size_t)b * 2048 + col;
        #pragma unroll
        for (int g = 0; g < 4; ++g) gxv[g] = *(const f32x2*)(gx + g * 512);
    }

    // ---- publish h_0 = 0 (my cells); per-WAVE flag := 1 after drain ----
    { f16x2 z; z[0] = (_Float16)0.f; z[1] = (_Float16)0.f;
      st_ic_u32((unsigned int*)(hbuf + b * 512 + col),
                __builtin_bit_cast(unsigned int, z)); }
    asm volatile("s_waitcnt vmcnt(0)" ::: "memory");
    unsigned int* myflag = flags + (size_t)(wg * 4 + wv) * 16;  // 64B spacing
    if (lane == 0) st_ic_u32(myflag, 1u);

    // consumer wave wv needs producers (BG, CG'=4wv+c) waves w', c,w' in 0..3
    // lane -> c = lane&3, w' = (lane>>2)&3  (lanes 16..63 mirror lane&15)
    const unsigned int* pollp =
        flags + (size_t)(((BG * 16 + wv * 4 + (lane & 3)) * 4
                          + ((lane >> 2) & 3)) ) * 16;

    // ---- B fragments: wave wv's 8 n-tiles x 4 K-frags (128 VGPRs) ----
    f16x8 bfr[8][4];
    #pragma unroll
    for (int n = 0; n < 8; ++n) {
        const int rr = n * 16 + m16;
        const int gr = (rr >> 5) * 512 + CG * 32 + (rr & 31);
        const float* wrow = Whh + (size_t)gr * 512 + wv * 128 + q * 8;
        #pragma unroll
        for (int ks = 0; ks < 4; ++ks) {
            const f32x4 w0 = *(const f32x4*)(wrow + ks * 32);
            const f32x4 w1 = *(const f32x4*)(wrow + ks * 32 + 4);
            f16x8 bv;
            #pragma unroll
            for (int e = 0; e < 4; ++e) {
                bv[e]     = (_Float16)w0[e];
                bv[4 + e] = (_Float16)w1[e];
            }
            bfr[n][ks] = bv;
        }
    }

    // ---- P-row pipeline: ppv = row for step t, loaded one step ahead ----
    int tok1;
    f32x2 ppv[4], ppn[4];
    {
        const int tok0 = toks[0];
        const float* pp = P + (size_t)tok0 * 2048 + col;
        #pragma unroll
        for (int g = 0; g < 4; ++g) ppv[g] = *(const f32x2*)(pp + g * 512);
        tok1 = toks[1];
    }

    float c0 = 0.f, c1 = 0.f;

    for (int t = 0; t < 512; ++t) {
        const unsigned int tgt = (unsigned int)(t + 1);

        // ---- per-wave arrival detection: poll my 16 producer-wave flags ----
        while (true) {
            const unsigned int v = ld_ic_u32(pollp);
            if (__all((int)(v >= tgt))) break;
        }
        asm volatile("" ::: "memory");

        const _Float16* hsrc = hbuf + (size_t)(t & 1) * (64 * 512);
        _Float16*       hdst = hbuf + (size_t)((t + 1) & 1) * (64 * 512);

        // ---- A fragments: 4 x dwordx4 sc1 (4KB/wave from IC) ----
        u32x4 a0, a1, a2, a3;
        {
            const _Float16* ap =
                hsrc + (BG * 16 + m16) * 512 + wv * 128 + q * 8;
            asm volatile(
                "global_load_dwordx4 %0, %4, off sc1\n\t"
                "global_load_dwordx4 %1, %4, off offset:64 sc1\n\t"
                "global_load_dwordx4 %2, %4, off offset:128 sc1\n\t"
                "global_load_dwordx4 %3, %4, off offset:192 sc1\n\t"
                "s_waitcnt vmcnt(0)"
                : "=&v"(a0), "=&v"(a1), "=&v"(a2), "=&v"(a3)
                : "v"(ap)
                : "memory");
        }
        f16x8 af[4] = {
            __builtin_bit_cast(f16x8, a0), __builtin_bit_cast(f16x8, a1),
            __builtin_bit_cast(f16x8, a2), __builtin_bit_cast(f16x8, a3)
        };

        // ---- prefetch NEXT step's P row (off critical chain) ----
        {
            const float* ppn_ptr = P + (size_t)tok1 * 2048 + col;
            #pragma unroll
            for (int g = 0; g < 4; ++g)
                ppn[g] = *(const f32x2*)(ppn_ptr + g * 512);
            tok1 = toks[t < 510 ? t + 2 : 511];
        }

        // ---- 32 MFMA: 8 n-tiles x 4 K-steps (my K-chunk partial) ----
        f32x4 acc[8] = {};
        #pragma unroll
        for (int ks = 0; ks < 4; ++ks)
            #pragma unroll
            for (int n = 0; n < 8; ++n)
                acc[n] = __builtin_amdgcn_mfma_f32_16x16x32_f16(
                    af[ks], bfr[n][ks], acc[n], 0, 0, 0);

        // ---- partial S -> LDS (pitch 17: 2-way max on reduce reads) ----
        float* sp = &Spart[t & 1][0];
        {
            const int cl = lane & 15, r0 = (lane >> 4) * 4;
            #pragma unroll
            for (int n = 0; n < 8; ++n) {
                const int base = (wv * 128 + n * 16 + cl) * 17 + r0;
                #pragma unroll
                for (int r = 0; r < 4; ++r) sp[base + r] = acc[n][r];
            }
        }
        __syncthreads();                  // split-K reduction barrier (only one)

        // ---- reduce 4 wave-partials per gate value ----
        f32x2 sv[4];
        #pragma unroll
        for (int g = 0; g < 4; ++g) {
            float s0 = 0.f, s1 = 0.f;
            #pragma unroll
            for (int w = 0; w < 4; ++w) {
                const int base = (w * 128 + g * 32 + cq) * 17 + bl;
                s0 += sp[base];
                s1 += sp[base + 17];
            }
            sv[g][0] = s0; sv[g][1] = s1;
        }

        // ---- gates (2 adjacent cols of one batch per thread) ----
        float hv[2];
        #pragma unroll
        for (int p = 0; p < 2; ++p) {
            const float iv = sigm_(sv[0][p] + gxv[0][p] + ppv[0][p]);
            const float fv = sigm_(sv[1][p] + gxv[1][p] + ppv[1][p]);
            const float gv = tanh_(sv[2][p] + gxv[2][p] + ppv[2][p]);
            const float ov = sigm_(sv[3][p] + gxv[3][p] + ppv[3][p]);
            float& c = p ? c1 : c0;
            c = fv * c + iv * gv;
            hv[p] = ov * tanh_(c);
        }

        // ---- publish h_{t+1} (f16 via proven intrinsic) ----
        f16x2 hh; hh[0] = (_Float16)hv[0]; hh[1] = (_Float16)hv[1];
        st_ic_u32((unsigned int*)(hdst + b * 512 + col),
                  __builtin_bit_cast(unsigned int, hh));
        if (t == last) {
            f32x2 o; o[0] = hv[0]; o[1] = hv[1];
            *(f32x2*)(hn + (size_t)b * 512 + col) = o;
        }

        // ---- per-WAVE release: drain my wave's stores, lane0 flag ----
        asm volatile("s_waitcnt vmcnt(0)" ::: "memory");
        if (lane == 0) st_ic_u32(myflag, (unsigned int)(t + 2));

        // shift the P pipeline
        #pragma unroll
        for (int g = 0; g < 4; ++g) ppv[g] = ppn[g];
    }
}

// ---------------------------------------------------------------------------
extern "C" void kernel_launch(void* const* d_in, const int* in_sizes, int n_in,
                              void* d_out, int out_size, void* d_ws, size_t ws_size,
                              hipStream_t stream)
{
    const float* x1    = (const float*)d_in[0];   // [64,1024]
    const int*   x2    = (const int*)  d_in[1];   // [64,512]
    const int*   lens  = (const int*)  d_in[2];   // [64]
    const float* emb   = (const float*)d_in[3];   // [512,128]
    const float* W_ih  = (const float*)d_in[4];   // [2048,1152]
    const float* W_hh  = (const float*)d_in[5];   // [2048,512]
    const float* b_ih  = (const float*)d_in[6];   // [2048]
    const float* b_hh  = (const float*)d_in[7];   // [2048]
    const float* W_act = (const float*)d_in[8];   // [512,512]
    const float* b_act = (const float*)d_in[9];   // [512]
    float* out = (float*)d_out;                   // [64,512]

    char* ws = (char*)d_ws;
    float*        GX0   = (float*)(ws + WS_GX0);
    float*        P     = (float*)(ws + WS_P);
    float*        hn    = (float*)(ws + WS_HN);
    _Float16*     hbuf  = (_Float16*)(ws + WS_HBUF);
    unsigned int* flags = (unsigned int*)(ws + WS_FLAGS);

    // zero flags + k-split accumulators (ws/out poisoned 0xAA each call)
    hipMemsetAsync(flags, 0, 16384, stream);
    hipMemsetAsync(GX0, 0, 64 * 2048 * sizeof(float), stream);
    hipMemsetAsync(out, 0, 64 * 512 * sizeof(float), stream);

    // GX0 = x1 @ W_ih[:, :1024]^T + b_ih + b_hh    (K=1024, 4-way K-split)
    gemm_nt_bias<<<dim3(32, 1, 4), TPB, 0, stream>>>(
        x1, 1024, W_ih, 1152, GX0, 2048, 1024, b_ih, b_hh);
    // P = emb @ W_ih[:, 1024:]^T                   (K=128)
    gemm_nt_bias<<<dim3(32, 8, 1), TPB, 0, stream>>>(
        emb, 128, W_ih + 1024, 1152, P, 2048, 128, nullptr, nullptr);

    // recurrence: 64 WGs, 2-D partition, per-wave flags, one barrier/step
    lstm_seq<<<NWG, TPB, 0, stream>>>(W_hh, GX0, P, x2, lens, hbuf, hn, flags);

    // out = hn @ W_act^T + b_act                   (K=512, 4-way K-split)
    gemm_nt_bias<<<dim3(8, 1, 4), TPB, 0, stream>>>(
        hn, 512, W_act, 512, out, 512, 512, b_act, nullptr);
}

// Round 11
// 1688.782 us; speedup vs baseline: 1.0557x; 1.0557x over previous
//
#include <hip/hip_runtime.h>
#include <cstdint>
#include <cstddef>

// ===========================================================================
// ActionDecoder on MI355X — round 11: r7 sync topology + r10 LDS fix +
// LDS-atomic release (no second barrier, no extra IC traffic).
// Topology: 64 WGs, WG w = (BG = w>>4, CG = w&15) owns batch-group BG
// (16 batches) x col-group CG (32 h-cols = 128 gate rows of W_hh). Wave wv
// takes K-chunk [128wv,128wv+128): B-frags in 128 VGPRs; split-K partial S
// reduced in LDS (double-buffered, pitch 17, ONE __syncthreads/step).
// Sync per step (cheapest measured): consumers poll 4 per-WG flags/wave;
// producers release via per-wave vmcnt(0) drain -> LDS ds_add_rtn counter;
// the LAST wave stores the single WG flag (64 flag stores/step device-wide,
// as r7 — r10's 256 regressed). Safety: h_{t+1} stores sit after the reduce
// barrier, which sits after all 4 waves' polls (union = all 16 producer WGs
// >= t+1 => all step-(t-1) reads of the overwritten buffer completed).
// Cross-WG data: f16 h + flags via relaxed agent-scope intrinsics (sc1,
// IC-coherent, no fences) — the proven r3..r7 primitives.
// ===========================================================================

typedef _Float16     f16x8 __attribute__((ext_vector_type(8)));
typedef _Float16     f16x2 __attribute__((ext_vector_type(2)));
typedef float        f32x4 __attribute__((ext_vector_type(4)));
typedef float        f32x2 __attribute__((ext_vector_type(2)));
typedef unsigned int u32x4 __attribute__((ext_vector_type(4)));

#define TPB 256
#define NWG 64

// ---- ws layout (bytes) ----
#define WS_GX0   0          // 64*2048 f32   = 524288
#define WS_P     524288     // 512*2048 f32  = 4194304
#define WS_HN    4718592    // 64*512 f32    = 131072
#define WS_HBUF  4849664    // 2*64*512 f16  = 131072
#define WS_FLAGS 4980736    // 64 WG x 256B  = 16384

__device__ __forceinline__ float sigm_(float x) { return 1.f / (1.f + __expf(-x)); }
__device__ __forceinline__ float tanh_(float x) {
    const float e = __expf(-2.f * fabsf(x));
    return copysignf((1.f - e) / (1.f + e), x);
}

// agent-scope (IC-coherent) relaxed accessors — proven r3..r7 primitives
__device__ __forceinline__ void st_ic_u32(unsigned int* p, unsigned int v) {
    __hip_atomic_store(p, v, __ATOMIC_RELAXED, __HIP_MEMORY_SCOPE_AGENT);
}
__device__ __forceinline__ unsigned int ld_ic_u32(const unsigned int* p) {
    return __hip_atomic_load(p, __ATOMIC_RELAXED, __HIP_MEMORY_SCOPE_AGENT);
}

// ---------------------------------------------------------------------------
// Generic f32 tiled GEMM: C[M,N] = A[M,K] @ B[N,K]^T (+bias1+bias2 on z==0).
// ---------------------------------------------------------------------------
__global__ void gemm_nt_bias(const float* __restrict__ A, int lda,
                             const float* __restrict__ B, int ldb,
                             float* __restrict__ C, int ldc, int K,
                             const float* __restrict__ bias1,
                             const float* __restrict__ bias2)
{
    __shared__ float As[32 * 68];
    __shared__ float Bs[32 * 68];
    const int tid = threadIdx.x;
    const int m0 = blockIdx.y * 64, n0 = blockIdx.x * 64;
    const int kchunk = K / gridDim.z;
    const int kbeg = blockIdx.z * kchunk, kend = kbeg + kchunk;
    const int tr = tid >> 4, tc = tid & 15;
    float acc[4][4] = {};

    for (int k0 = kbeg; k0 < kend; k0 += 32) {
        __syncthreads();
        #pragma unroll
        for (int idx = tid; idx < 2048; idx += TPB) {
            const int r = idx >> 5, kk = idx & 31;
            As[kk * 68 + r] = A[(size_t)(m0 + r) * lda + k0 + kk];
            Bs[kk * 68 + r] = B[(size_t)(n0 + r) * ldb + k0 + kk];
        }
        __syncthreads();
        #pragma unroll
        for (int kk = 0; kk < 32; ++kk) {
            const f32x4 a = *(const f32x4*)&As[kk * 68 + tr * 4];
            const f32x4 b = *(const f32x4*)&Bs[kk * 68 + tc * 4];
            #pragma unroll
            for (int i = 0; i < 4; ++i)
                #pragma unroll
                for (int j = 0; j < 4; ++j)
                    acc[i][j] = fmaf(a[i], b[j], acc[i][j]);
        }
    }

    const bool split = (gridDim.z > 1);
    #pragma unroll
    for (int i = 0; i < 4; ++i) {
        const int m = m0 + tr * 4 + i;
        #pragma unroll
        for (int j = 0; j < 4; ++j) {
            const int n = n0 + tc * 4 + j;
            float v = acc[i][j];
            if (blockIdx.z == 0) {
                if (bias1) v += bias1[n];
                if (bias2) v += bias2[n];
            }
            if (split) atomicAdd(&C[(size_t)m * ldc + n], v);
            else       C[(size_t)m * ldc + n] = v;
        }
    }
}

// ---------------------------------------------------------------------------
// LSTM recurrence. 64 WGs x 256 threads. Single WG flag, LDS-atomic release.
// ---------------------------------------------------------------------------
__global__ void __launch_bounds__(TPB, 1)
lstm_seq(const float* __restrict__ Whh,   // [2048,512] f32
         const float* __restrict__ GX0,   // [64,2048] f32 (ws)
         const float* __restrict__ P,     // [512,2048] f32 (ws)
         const int*   __restrict__ x2,    // [64,512]
         const int*   __restrict__ lens,  // [64]
         _Float16*    hbuf,               // [2][64*512] f16 (ws, IC-resident)
         float*       __restrict__ hn,    // [64,512] f32 (ws)
         unsigned int* flags)             // [64 wg] spaced 256B
{
    // Spart[buf][wv][rowloc(128)][batch(16)+pad1], pitch 17 => 69632 B
    __shared__ float Spart[2][4 * 128 * 17];
    __shared__ unsigned int s_cnt;        // release counter (monotonic)

    const int tid = threadIdx.x, wg = blockIdx.x;
    const int lane = tid & 63, wv = tid >> 6;
    const int BG = wg >> 4;               // batch group 0..3
    const int CG = wg & 15;               // col group 0..15
    const int m16 = lane & 15, q = lane >> 4;

    // ---- gate-thread geometry: thread -> (batch-loc, 2 adjacent cols) ----
    const int bl  = tid >> 4;             // 0..15 batch-local
    const int cq  = (tid & 15) * 2;       // 0,2,..,30 col-local
    const int b   = BG * 16 + bl;
    const int col = CG * 32 + cq;
    const int last = lens[b] - 1;
    const int* toks = x2 + b * 512;

    if (tid == 0) s_cnt = 0u;
    __syncthreads();

    // ---- time-invariant gate inputs from GX0 (hoisted) ----
    f32x2 gxv[4];
    {
        const float* gx = GX0 + (size_t)b * 2048 + col;
        #pragma unroll
        for (int g = 0; g < 4; ++g) gxv[g] = *(const f32x2*)(gx + g * 512);
    }

    // ---- publish h_0 = 0 (my cells); LDS-atomic release -> flag := 1 ----
    unsigned int* myflag = flags + (size_t)wg * 64;   // 256B spacing
    { f16x2 z; z[0] = (_Float16)0.f; z[1] = (_Float16)0.f;
      st_ic_u32((unsigned int*)(hbuf + b * 512 + col),
                __builtin_bit_cast(unsigned int, z)); }
    asm volatile("s_waitcnt vmcnt(0)" ::: "memory");
    if (lane == 0) {
        const unsigned int prev = atomicAdd(&s_cnt, 1u);
        if (prev == 3u) st_ic_u32(myflag, 1u);
    }

    // wave wv consumes h-cols [128wv,128wv+128) of batch group BG,
    // produced by WGs (BG, 4wv+0..3): poll those 4 flags (lane&3).
    const unsigned int* pollp =
        flags + (size_t)(BG * 16 + wv * 4 + (lane & 3)) * 64;

    // ---- B fragments: wave wv's 8 n-tiles x 4 K-frags (128 VGPRs) ----
    f16x8 bfr[8][4];
    #pragma unroll
    for (int n = 0; n < 8; ++n) {
        const int rr = n * 16 + m16;
        const int gr = (rr >> 5) * 512 + CG * 32 + (rr & 31);
        const float* wrow = Whh + (size_t)gr * 512 + wv * 128 + q * 8;
        #pragma unroll
        for (int ks = 0; ks < 4; ++ks) {
            const f32x4 w0 = *(const f32x4*)(wrow + ks * 32);
            const f32x4 w1 = *(const f32x4*)(wrow + ks * 32 + 4);
            f16x8 bv;
            #pragma unroll
            for (int e = 0; e < 4; ++e) {
                bv[e]     = (_Float16)w0[e];
                bv[4 + e] = (_Float16)w1[e];
            }
            bfr[n][ks] = bv;
        }
    }

    // ---- P-row pipeline: ppv = row for step t, loaded one step ahead ----
    int tok1;
    f32x2 ppv[4], ppn[4];
    {
        const int tok0 = toks[0];
        const float* pp = P + (size_t)tok0 * 2048 + col;
        #pragma unroll
        for (int g = 0; g < 4; ++g) ppv[g] = *(const f32x2*)(pp + g * 512);
        tok1 = toks[1];
    }

    float c0 = 0.f, c1 = 0.f;

    for (int t = 0; t < 512; ++t) {
        const unsigned int tgt = (unsigned int)(t + 1);

        // ---- per-wave arrival detection: poll my 4 producer flags ----
        while (true) {
            const unsigned int v = ld_ic_u32(pollp);
            if (__all((int)(v >= tgt))) break;
        }
        asm volatile("" ::: "memory");

        const _Float16* hsrc = hbuf + (size_t)(t & 1) * (64 * 512);
        _Float16*       hdst = hbuf + (size_t)((t + 1) & 1) * (64 * 512);

        // ---- A fragments: 4 x dwordx4 sc1 (4KB/wave from IC) ----
        u32x4 a0, a1, a2, a3;
        {
            const _Float16* ap =
                hsrc + (BG * 16 + m16) * 512 + wv * 128 + q * 8;
            asm volatile(
                "global_load_dwordx4 %0, %4, off sc1\n\t"
                "global_load_dwordx4 %1, %4, off offset:64 sc1\n\t"
                "global_load_dwordx4 %2, %4, off offset:128 sc1\n\t"
                "global_load_dwordx4 %3, %4, off offset:192 sc1\n\t"
                "s_waitcnt vmcnt(0)"
                : "=&v"(a0), "=&v"(a1), "=&v"(a2), "=&v"(a3)
                : "v"(ap)
                : "memory");
        }
        f16x8 af[4] = {
            __builtin_bit_cast(f16x8, a0), __builtin_bit_cast(f16x8, a1),
            __builtin_bit_cast(f16x8, a2), __builtin_bit_cast(f16x8, a3)
        };

        // ---- prefetch NEXT step's P row (off critical chain) ----
        {
            const float* ppn_ptr = P + (size_t)tok1 * 2048 + col;
            #pragma unroll
            for (int g = 0; g < 4; ++g)
                ppn[g] = *(const f32x2*)(ppn_ptr + g * 512);
            tok1 = toks[t < 510 ? t + 2 : 511];
        }

        // ---- 32 MFMA: 8 n-tiles x 4 K-steps (my K-chunk partial) ----
        f32x4 acc[8] = {};
        #pragma unroll
        for (int ks = 0; ks < 4; ++ks)
            #pragma unroll
            for (int n = 0; n < 8; ++n)
                acc[n] = __builtin_amdgcn_mfma_f32_16x16x32_f16(
                    af[ks], bfr[n][ks], acc[n], 0, 0, 0);

        // ---- partial S -> LDS (pitch 17: ~2-way max conflicts) ----
        float* sp = &Spart[t & 1][0];
        {
            const int cl = lane & 15, r0 = (lane >> 4) * 4;
            #pragma unroll
            for (int n = 0; n < 8; ++n) {
                const int base = (wv * 128 + n * 16 + cl) * 17 + r0;
                #pragma unroll
                for (int r = 0; r < 4; ++r) sp[base + r] = acc[n][r];
            }
        }
        __syncthreads();                  // split-K reduction barrier (only one)

        // ---- reduce 4 wave-partials per gate value ----
        f32x2 sv[4];
        #pragma unroll
        for (int g = 0; g < 4; ++g) {
            float s0 = 0.f, s1 = 0.f;
            #pragma unroll
            for (int w = 0; w < 4; ++w) {
                const int base = (w * 128 + g * 32 + cq) * 17 + bl;
                s0 += sp[base];
                s1 += sp[base + 17];
            }
            sv[g][0] = s0; sv[g][1] = s1;
        }

        // ---- gates (2 adjacent cols of one batch per thread) ----
        float hv[2];
        #pragma unroll
        for (int p = 0; p < 2; ++p) {
            const float iv = sigm_(sv[0][p] + gxv[0][p] + ppv[0][p]);
            const float fv = sigm_(sv[1][p] + gxv[1][p] + ppv[1][p]);
            const float gv = tanh_(sv[2][p] + gxv[2][p] + ppv[2][p]);
            const float ov = sigm_(sv[3][p] + gxv[3][p] + ppv[3][p]);
            float& c = p ? c1 : c0;
            c = fv * c + iv * gv;
            hv[p] = ov * tanh_(c);
        }

        // ---- publish h_{t+1} (f16 via proven intrinsic) ----
        f16x2 hh; hh[0] = (_Float16)hv[0]; hh[1] = (_Float16)hv[1];
        st_ic_u32((unsigned int*)(hdst + b * 512 + col),
                  __builtin_bit_cast(unsigned int, hh));
        if (t == last) {
            f32x2 o; o[0] = hv[0]; o[1] = hv[1];
            *(f32x2*)(hn + (size_t)b * 512 + col) = o;
        }

        // ---- release: per-wave drain -> LDS counter; LAST wave flags ----
        asm volatile("s_waitcnt vmcnt(0)" ::: "memory");
        if (lane == 0) {
            const unsigned int prev = atomicAdd(&s_cnt, 1u);
            if (prev == (unsigned int)(4 * t + 7))
                st_ic_u32(myflag, (unsigned int)(t + 2));
        }

        // shift the P pipeline
        #pragma unroll
        for (int g = 0; g < 4; ++g) ppv[g] = ppn[g];
    }
}

// ---------------------------------------------------------------------------
extern "C" void kernel_launch(void* const* d_in, const int* in_sizes, int n_in,
                              void* d_out, int out_size, void* d_ws, size_t ws_size,
                              hipStream_t stream)
{
    const float* x1    = (const float*)d_in[0];   // [64,1024]
    const int*   x2    = (const int*)  d_in[1];   // [64,512]
    const int*   lens  = (const int*)  d_in[2];   // [64]
    const float* emb   = (const float*)d_in[3];   // [512,128]
    const float* W_ih  = (const float*)d_in[4];   // [2048,1152]
    const float* W_hh  = (const float*)d_in[5];   // [2048,512]
    const float* b_ih  = (const float*)d_in[6];   // [2048]
    const float* b_hh  = (const float*)d_in[7];   // [2048]
    const float* W_act = (const float*)d_in[8];   // [512,512]
    const float* b_act = (const float*)d_in[9];   // [512]
    float* out = (float*)d_out;                   // [64,512]

    char* ws = (char*)d_ws;
    float*        GX0   = (float*)(ws + WS_GX0);
    float*        P     = (float*)(ws + WS_P);
    float*        hn    = (float*)(ws + WS_HN);
    _Float16*     hbuf  = (_Float16*)(ws + WS_HBUF);
    unsigned int* flags = (unsigned int*)(ws + WS_FLAGS);

    // zero flags + k-split accumulators (ws/out poisoned 0xAA each call)
    hipMemsetAsync(flags, 0, 16384, stream);
    hipMemsetAsync(GX0, 0, 64 * 2048 * sizeof(float), stream);
    hipMemsetAsync(out, 0, 64 * 512 * sizeof(float), stream);

    // GX0 = x1 @ W_ih[:, :1024]^T + b_ih + b_hh    (K=1024, 4-way K-split)
    gemm_nt_bias<<<dim3(32, 1, 4), TPB, 0, stream>>>(
        x1, 1024, W_ih, 1152, GX0, 2048, 1024, b_ih, b_hh);
    // P = emb @ W_ih[:, 1024:]^T                   (K=128)
    gemm_nt_bias<<<dim3(32, 8, 1), TPB, 0, stream>>>(
        emb, 128, W_ih + 1024, 1152, P, 2048, 128, nullptr, nullptr);

    // recurrence: 64 WGs, 2-D partition, 4-flag polls, LDS-atomic release
    lstm_seq<<<NWG, TPB, 0, stream>>>(W_hh, GX0, P, x2, lens, hbuf, hn, flags);

    // out = hn @ W_act^T + b_act                   (K=512, 4-way K-split)
    gemm_nt_bias<<<dim3(8, 1, 4), TPB, 0, stream>>>(
        hn, 512, W_act, 512, out, 512, 512, b_act, nullptr);
}

// Round 12
// 1476.047 us; speedup vs baseline: 1.2078x; 1.1441x over previous
//
#include <hip/hip_runtime.h>
#include <cstdint>
#include <cstddef>

// ===========================================================================
// ActionDecoder on MI355X — round 12: EXACT r7 (proven best, 2.62us/step)
// + ONE change: P-row prefetch moved AFTER the release flag store.
// Rationale: __syncthreads drains ALL outstanding VMEM (compiler emits
// s_waitcnt vmcnt(0) before s_barrier), so r7's mid-step P prefetch put its
// HBM misses (~900cy) on the critical path at BOTH barriers. Issuing the
// next step's P loads after the flag store parks their latency in the poll
// window where it is harmless.
// Topology (r7): 64 WGs, WG w = (BG = w>>4, CG = w&15) owns batch-group BG
// (16 batches) x col-group CG (32 h-cols = 128 gate rows of W_hh). Wave wv
// takes K-chunk [128wv,128wv+128): B-frags in 128 VGPRs; split-K partial S
// in single-buffered LDS (pitch 20, b128 writes), two __syncthreads/step
// (reduce barrier + release barrier), tid0 stores the single WG flag;
// consumers poll 4 producer flags per wave. Cross-WG data/flags: relaxed
// agent-scope intrinsics (sc1 -> IC-coherent, no fences).
// ===========================================================================

typedef _Float16     f16x8 __attribute__((ext_vector_type(8)));
typedef _Float16     f16x2 __attribute__((ext_vector_type(2)));
typedef float        f32x4 __attribute__((ext_vector_type(4)));
typedef float        f32x2 __attribute__((ext_vector_type(2)));
typedef unsigned int u32x4 __attribute__((ext_vector_type(4)));

#define TPB 256
#define NWG 64

// ---- ws layout (bytes) ----
#define WS_GX0   0          // 64*2048 f32   = 524288
#define WS_P     524288     // 512*2048 f32  = 4194304
#define WS_HN    4718592    // 64*512 f32    = 131072
#define WS_HBUF  4849664    // 2*64*512 f16  = 131072
#define WS_FLAGS 4980736    // 64 WG x 256B  = 16384

__device__ __forceinline__ float sigm_(float x) { return 1.f / (1.f + __expf(-x)); }
__device__ __forceinline__ float tanh_(float x) {
    const float e = __expf(-2.f * fabsf(x));
    return copysignf((1.f - e) / (1.f + e), x);
}

// agent-scope (IC-coherent) relaxed accessors — proven r3..r7 primitives
__device__ __forceinline__ void st_ic_u32(unsigned int* p, unsigned int v) {
    __hip_atomic_store(p, v, __ATOMIC_RELAXED, __HIP_MEMORY_SCOPE_AGENT);
}
__device__ __forceinline__ unsigned int ld_ic_u32(const unsigned int* p) {
    return __hip_atomic_load(p, __ATOMIC_RELAXED, __HIP_MEMORY_SCOPE_AGENT);
}

// ---------------------------------------------------------------------------
// Generic f32 tiled GEMM: C[M,N] = A[M,K] @ B[N,K]^T (+bias1+bias2 on z==0).
// ---------------------------------------------------------------------------
__global__ void gemm_nt_bias(const float* __restrict__ A, int lda,
                             const float* __restrict__ B, int ldb,
                             float* __restrict__ C, int ldc, int K,
                             const float* __restrict__ bias1,
                             const float* __restrict__ bias2)
{
    __shared__ float As[32 * 68];
    __shared__ float Bs[32 * 68];
    const int tid = threadIdx.x;
    const int m0 = blockIdx.y * 64, n0 = blockIdx.x * 64;
    const int kchunk = K / gridDim.z;
    const int kbeg = blockIdx.z * kchunk, kend = kbeg + kchunk;
    const int tr = tid >> 4, tc = tid & 15;
    float acc[4][4] = {};

    for (int k0 = kbeg; k0 < kend; k0 += 32) {
        __syncthreads();
        #pragma unroll
        for (int idx = tid; idx < 2048; idx += TPB) {
            const int r = idx >> 5, kk = idx & 31;
            As[kk * 68 + r] = A[(size_t)(m0 + r) * lda + k0 + kk];
            Bs[kk * 68 + r] = B[(size_t)(n0 + r) * ldb + k0 + kk];
        }
        __syncthreads();
        #pragma unroll
        for (int kk = 0; kk < 32; ++kk) {
            const f32x4 a = *(const f32x4*)&As[kk * 68 + tr * 4];
            const f32x4 b = *(const f32x4*)&Bs[kk * 68 + tc * 4];
            #pragma unroll
            for (int i = 0; i < 4; ++i)
                #pragma unroll
                for (int j = 0; j < 4; ++j)
                    acc[i][j] = fmaf(a[i], b[j], acc[i][j]);
        }
    }

    const bool split = (gridDim.z > 1);
    #pragma unroll
    for (int i = 0; i < 4; ++i) {
        const int m = m0 + tr * 4 + i;
        #pragma unroll
        for (int j = 0; j < 4; ++j) {
            const int n = n0 + tc * 4 + j;
            float v = acc[i][j];
            if (blockIdx.z == 0) {
                if (bias1) v += bias1[n];
                if (bias2) v += bias2[n];
            }
            if (split) atomicAdd(&C[(size_t)m * ldc + n], v);
            else       C[(size_t)m * ldc + n] = v;
        }
    }
}

// ---------------------------------------------------------------------------
// LSTM recurrence. 64 WGs x 256 threads. 2-D partition, split-K per wave.
// ---------------------------------------------------------------------------
__global__ void __launch_bounds__(TPB, 1)
lstm_seq(const float* __restrict__ Whh,   // [2048,512] f32
         const float* __restrict__ GX0,   // [64,2048] f32 (ws)
         const float* __restrict__ P,     // [512,2048] f32 (ws)
         const int*   __restrict__ x2,    // [64,512]
         const int*   __restrict__ lens,  // [64]
         _Float16*    hbuf,               // [2][64*512] f16 (ws, IC-resident)
         float*       __restrict__ hn,    // [64,512] f32 (ws)
         unsigned int* flags)             // [64 wg] spaced 256B
{
    // Spart[wv][rowloc(128)][batch(16)+pad4] f32 = 40960 B (r7 layout)
    __shared__ float Spart[4 * 128 * 20];

    const int tid = threadIdx.x, wg = blockIdx.x;
    const int lane = tid & 63, wv = tid >> 6;
    const int BG = wg >> 4;               // batch group 0..3
    const int CG = wg & 15;               // col group 0..15
    const int m16 = lane & 15, q = lane >> 4;

    // ---- gate-thread geometry: thread -> (batch-loc, 2 adjacent cols) ----
    const int bl  = tid >> 4;             // 0..15 batch-local
    const int cq  = (tid & 15) * 2;       // 0,2,..,30 col-local
    const int b   = BG * 16 + bl;
    const int col = CG * 32 + cq;
    const int last = lens[b] - 1;
    const int* toks = x2 + b * 512;

    // ---- time-invariant gate inputs from GX0 (hoisted) ----
    f32x2 gxv[4];
    {
        const float* gx = GX0 + (size_t)b * 2048 + col;
        #pragma unroll
        for (int g = 0; g < 4; ++g) gxv[g] = *(const f32x2*)(gx + g * 512);
    }

    // ---- publish h_0 = 0 (my cells); WG flag := 1 ----
    { f16x2 z; z[0] = (_Float16)0.f; z[1] = (_Float16)0.f;
      st_ic_u32((unsigned int*)(hbuf + b * 512 + col),
                __builtin_bit_cast(unsigned int, z)); }
    __syncthreads();                      // drains vmcnt of all waves
    unsigned int* myflag = flags + (size_t)wg * 64;   // 256B spacing
    if (tid == 0) st_ic_u32(myflag, 1u);

    // wave wv consumes h-cols [128wv,128wv+128) of batch group BG,
    // produced by WGs (BG, 4wv+0..3): poll those 4 flags (lane&3).
    const unsigned int* pollp =
        flags + (size_t)(BG * 16 + wv * 4 + (lane & 3)) * 64;

    // ---- B fragments: wave wv's 8 n-tiles x 4 K-frags (128 VGPRs) ----
    f16x8 bfr[8][4];
    #pragma unroll
    for (int n = 0; n < 8; ++n) {
        const int rr = n * 16 + m16;
        const int gr = (rr >> 5) * 512 + CG * 32 + (rr & 31);
        const float* wrow = Whh + (size_t)gr * 512 + wv * 128 + q * 8;
        #pragma unroll
        for (int ks = 0; ks < 4; ++ks) {
            const f32x4 w0 = *(const f32x4*)(wrow + ks * 32);
            const f32x4 w1 = *(const f32x4*)(wrow + ks * 32 + 4);
            f16x8 bv;
            #pragma unroll
            for (int e = 0; e < 4; ++e) {
                bv[e]     = (_Float16)w0[e];
                bv[4 + e] = (_Float16)w1[e];
            }
            bfr[n][ks] = bv;
        }
    }

    // ---- P-row pipeline: ppv = row for step t; refilled post-release ----
    int tok1;
    f32x2 ppv[4];
    {
        const int tok0 = toks[0];
        const float* pp = P + (size_t)tok0 * 2048 + col;
        #pragma unroll
        for (int g = 0; g < 4; ++g) ppv[g] = *(const f32x2*)(pp + g * 512);
        tok1 = toks[1];
    }

    float c0 = 0.f, c1 = 0.f;

    for (int t = 0; t < 512; ++t) {
        const unsigned int tgt = (unsigned int)(t + 1);

        // ---- per-wave arrival detection: poll my 4 producer flags ----
        while (true) {
            const unsigned int v = ld_ic_u32(pollp);
            if (__all((int)(v >= tgt))) break;
        }
        asm volatile("" ::: "memory");

        const _Float16* hsrc = hbuf + (size_t)(t & 1) * (64 * 512);
        _Float16*       hdst = hbuf + (size_t)((t + 1) & 1) * (64 * 512);

        // ---- A fragments: 4 x dwordx4 sc1 (4KB/wave from IC) ----
        u32x4 a0, a1, a2, a3;
        {
            const _Float16* ap =
                hsrc + (BG * 16 + m16) * 512 + wv * 128 + q * 8;
            asm volatile(
                "global_load_dwordx4 %0, %4, off sc1\n\t"
                "global_load_dwordx4 %1, %4, off offset:64 sc1\n\t"
                "global_load_dwordx4 %2, %4, off offset:128 sc1\n\t"
                "global_load_dwordx4 %3, %4, off offset:192 sc1\n\t"
                "s_waitcnt vmcnt(0)"
                : "=&v"(a0), "=&v"(a1), "=&v"(a2), "=&v"(a3)
                : "v"(ap)
                : "memory");
        }
        f16x8 af[4] = {
            __builtin_bit_cast(f16x8, a0), __builtin_bit_cast(f16x8, a1),
            __builtin_bit_cast(f16x8, a2), __builtin_bit_cast(f16x8, a3)
        };

        // ---- 32 MFMA: 8 n-tiles x 4 K-steps (my K-chunk partial) ----
        f32x4 acc[8] = {};
        #pragma unroll
        for (int ks = 0; ks < 4; ++ks)
            #pragma unroll
            for (int n = 0; n < 8; ++n)
                acc[n] = __builtin_amdgcn_mfma_f32_16x16x32_f16(
                    af[ks], bfr[n][ks], acc[n], 0, 0, 0);

        // ---- write partial S to LDS: [wv][n*16+cl][r0..r0+3] (b128) ----
        {
            const int cl = lane & 15, r0 = (lane >> 4) * 4;
            #pragma unroll
            for (int n = 0; n < 8; ++n)
                *(f32x4*)&Spart[(wv * 128 + n * 16 + cl) * 20 + r0] = acc[n];
        }
        __syncthreads();                  // split-K reduction barrier

        // ---- gate inputs: sum 4 wave-partials per gate value ----
        f32x2 sv[4];
        #pragma unroll
        for (int g = 0; g < 4; ++g) {
            f32x2 s = {0.f, 0.f};
            #pragma unroll
            for (int w = 0; w < 4; ++w) {
                const int base = (w * 128 + g * 32 + cq) * 20 + bl;
                s[0] += Spart[base];
                s[1] += Spart[base + 20];
            }
            sv[g] = s;
        }

        // ---- gates (2 adjacent cols of one batch per thread) ----
        float hv[2];
        #pragma unroll
        for (int p = 0; p < 2; ++p) {
            const float iv = sigm_(sv[0][p] + gxv[0][p] + ppv[0][p]);
            const float fv = sigm_(sv[1][p] + gxv[1][p] + ppv[1][p]);
            const float gv = tanh_(sv[2][p] + gxv[2][p] + ppv[2][p]);
            const float ov = sigm_(sv[3][p] + gxv[3][p] + ppv[3][p]);
            float& c = p ? c1 : c0;
            c = fv * c + iv * gv;
            hv[p] = ov * tanh_(c);
        }

        f16x2 hh; hh[0] = (_Float16)hv[0]; hh[1] = (_Float16)hv[1];
        st_ic_u32((unsigned int*)(hdst + b * 512 + col),
                  __builtin_bit_cast(unsigned int, hh));
        if (t == last) {
            f32x2 o; o[0] = hv[0]; o[1] = hv[1];
            *(f32x2*)(hn + (size_t)b * 512 + col) = o;
        }

        // ---- release: barrier drains h stores ONLY (no P loads in
        //      flight now), then tid0 flag ----
        __syncthreads();
        if (tid == 0) st_ic_u32(myflag, (unsigned int)(t + 2));

        // ---- r12 change: NEXT step's P row prefetch issued POST-release;
        //      its (possibly HBM-miss) latency sits in the poll window ----
        {
            const float* pn = P + (size_t)tok1 * 2048 + col;
            #pragma unroll
            for (int g = 0; g < 4; ++g)
                ppv[g] = *(const f32x2*)(pn + g * 512);
            tok1 = toks[t < 510 ? t + 2 : 511];
        }
    }
}

// ---------------------------------------------------------------------------
extern "C" void kernel_launch(void* const* d_in, const int* in_sizes, int n_in,
                              void* d_out, int out_size, void* d_ws, size_t ws_size,
                              hipStream_t stream)
{
    const float* x1    = (const float*)d_in[0];   // [64,1024]
    const int*   x2    = (const int*)  d_in[1];   // [64,512]
    const int*   lens  = (const int*)  d_in[2];   // [64]
    const float* emb   = (const float*)d_in[3];   // [512,128]
    const float* W_ih  = (const float*)d_in[4];   // [2048,1152]
    const float* W_hh  = (const float*)d_in[5];   // [2048,512]
    const float* b_ih  = (const float*)d_in[6];   // [2048]
    const float* b_hh  = (const float*)d_in[7];   // [2048]
    const float* W_act = (const float*)d_in[8];   // [512,512]
    const float* b_act = (const float*)d_in[9];   // [512]
    float* out = (float*)d_out;                   // [64,512]

    char* ws = (char*)d_ws;
    float*        GX0   = (float*)(ws + WS_GX0);
    float*        P     = (float*)(ws + WS_P);
    float*        hn    = (float*)(ws + WS_HN);
    _Float16*     hbuf  = (_Float16*)(ws + WS_HBUF);
    unsigned int* flags = (unsigned int*)(ws + WS_FLAGS);

    // zero flags + k-split accumulators (ws/out poisoned 0xAA each call)
    hipMemsetAsync(flags, 0, 16384, stream);
    hipMemsetAsync(GX0, 0, 64 * 2048 * sizeof(float), stream);
    hipMemsetAsync(out, 0, 64 * 512 * sizeof(float), stream);

    // GX0 = x1 @ W_ih[:, :1024]^T + b_ih + b_hh    (K=1024, 4-way K-split)
    gemm_nt_bias<<<dim3(32, 1, 4), TPB, 0, stream>>>(
        x1, 1024, W_ih, 1152, GX0, 2048, 1024, b_ih, b_hh);
    // P = emb @ W_ih[:, 1024:]^T                   (K=128)
    gemm_nt_bias<<<dim3(32, 8, 1), TPB, 0, stream>>>(
        emb, 128, W_ih + 1024, 1152, P, 2048, 128, nullptr, nullptr);

    // recurrence: 64 WGs, 2-D partition, per-wave 4-flag polling
    lstm_seq<<<NWG, TPB, 0, stream>>>(W_hh, GX0, P, x2, lens, hbuf, hn, flags);

    // out = hn @ W_act^T + b_act                   (K=512, 4-way K-split)
    gemm_nt_bias<<<dim3(8, 1, 4), TPB, 0, stream>>>(
        hn, 512, W_act, 512, out, 512, 512, b_act, nullptr);
}